// Round 12
// baseline (957.679 us; speedup 1.0000x reference)
//
#include <hip/hip_runtime.h>
#include <stdint.h>

#define N_EDGES 2000000
#define NUM_SEG 500000
#define HID 128
#define NBLK 4
#define NWG 256             // persistent: one 8-wave wg per CU (LDS-forced)
#define GRP_ROWS 256        // rows per group iteration (8 waves x 32)
#define NGRP2 7813          // ceil(N_EDGES / 256); last group is partial

typedef __attribute__((ext_vector_type(8))) unsigned short ushort8;
typedef __attribute__((ext_vector_type(8))) __bf16 bf16x8;
typedef __attribute__((ext_vector_type(4))) float float4v;
typedef __attribute__((ext_vector_type(2))) uint32_t uint2v;

__device__ inline unsigned short f32_to_bf16(float f) {
    return __builtin_bit_cast(unsigned short, (__bf16)f);   // native cvt, RNE
}

__device__ inline uint32_t pack_bf16(float lo, float hi) {
#if __has_builtin(__builtin_amdgcn_cvt_pk_bf16_f32)
    typedef __attribute__((ext_vector_type(2))) __bf16 bf16x2;
    bf16x2 r = __builtin_amdgcn_cvt_pk_bf16_f32(lo, hi);
    return __builtin_bit_cast(uint32_t, r);
#else
    return (uint32_t)f32_to_bf16(lo) | ((uint32_t)f32_to_bf16(hi) << 16);
#endif
}

// ---- prep: WbF[blk] = bf16(W_res*rms_w) in A-FRAGMENT ORDER:
//   i = blk*16384 + (kt*8+ft)*512 + lane*8 + j -> W'[m=ft*16+(lane&15)][k=kt*32+(lane>>4)*8+j]
// Also packs Win4[f] = {W_in[f][0..2], b_in[f]} and zero-fills segsum.
__global__ void prep_kernel(const float* __restrict__ W_res,
                            const float* __restrict__ rms_w,
                            const float* __restrict__ W_in,
                            const float* __restrict__ b_in,
                            unsigned short* __restrict__ WbF,
                            float* __restrict__ Win4,
                            float* __restrict__ segsum) {
    int i = blockIdx.x * 256 + threadIdx.x;
    if (i < 65536) {
        int blk = i >> 14;
        int r = i & 16383;
        int j = r & 7, lane = (r >> 3) & 63, ft = (r >> 9) & 7, kt = r >> 12;
        int cc = lane & 15, qq = lane >> 4;
        int row = ft * 16 + cc;
        int k = kt * 32 + qq * 8 + j;
        WbF[i] = f32_to_bf16(W_res[blk * 16384 + row * HID + k] * rms_w[blk * HID + k]);
    } else if (i < 65536 + 128) {
        int f = i - 65536;
        Win4[f * 4 + 0] = W_in[f * 3 + 0];
        Win4[f * 4 + 1] = W_in[f * 3 + 1];
        Win4[f * 4 + 2] = W_in[f * 3 + 2];
        Win4[f * 4 + 3] = b_in[f];
    } else {
        int s = i - 65536 - 128;
        if (s < NUM_SEG) segsum[s] = 0.0f;
    }
}

// ---- fused MLP, R12 = R11 concept with CORRECT arithmetic.
// R11's NaN was an LDS overflow: W' is 128 KB total (4 x 16384 shorts), not 64 KB;
// the staging loop smashed hnF/Win4. All-4-blocks + full hn (194 KB) never fit.
// R12 composition (all pieces individually harness-proven):
//   - W blks 0-2 in LDS, 96 KB (R10 path; blk3 streams from L2 w/ 1-deep ping-pong)
//   - halved wave-private hnF, 4 KB/wave x 8 = 32 KB (R2/R3-verified layout:
//     write ft=0..3 -> read kt=0,1 -> write ft=4..7 same slots -> read kt=2,3;
//     in-order DS makes the WAR safe without barriers)
//   - Win4 2 KB. Total 133,120 B = R10's proven footprint -> 1 wg/CU.
//   - ONE 512-thread wg per CU: 8 waves = 2/SIMD by geometry (R7-proven).
//     launch_bounds(512,1): empirically arg2 ~ resident-wg multiplier ->
//     1 wg x 8 waves = 2 waves/EU -> 256-VGPR budget (R10-proven envelope).
// Tripwires: WRITE ~7.8 MB, FETCH ~12-13 MB, VGPR <= 256 (balloon = spill, void).
__launch_bounds__(512, 1)
__global__ void mlp_kernel(const float* __restrict__ x,           // [N,3]
                           const unsigned short* __restrict__ WbF,// [4,16384] bf16 A-frag order
                           const float* __restrict__ b_res,       // [4,128]
                           const float* __restrict__ W_out,       // [128]
                           const float* __restrict__ b_out,       // [1]
                           const float* __restrict__ Win4g,       // [128,4] = {w0,w1,w2,b_in}
                           float* __restrict__ e) {               // [N] = exp(logit)
    __shared__ __align__(16) unsigned short WsL[49152];   // 96 KB: W' blks 0..2, A-frag order
    __shared__ __align__(16) unsigned short hnF[16384];   // 32 KB: halved hn (4 KB/wave x 8)
    __shared__ __align__(16) float4v Win4[128];           // 2 KB

    const int t = threadIdx.x;
    const int wave = t >> 6;   // 0..7
    const int lane = t & 63;
    const int q = lane >> 4;   // quad within wave
    const int c = lane & 15;   // lane within quad

    // ---- one-time staging: W blks 0-2 -> LDS (12 x 16 B per thread), Win4
    #pragma unroll
    for (int i = 0; i < 12; ++i)
        *(ushort8*)&WsL[(i * 512 + t) * 8] = *(const ushort8*)&WbF[(i * 512 + t) * 8];
    if (t < 128) Win4[t] = ((const float4v*)Win4g)[t];

    // x for the first group (issued before the barrier; drains under it)
    float xr_c[2][3], xr_n[2][3];
    {
        long rb = (long)blockIdx.x * GRP_ROWS;
        #pragma unroll
        for (int rt = 0; rt < 2; ++rt) {
            long row = rb + wave * 32 + rt * 16 + c;
            #pragma unroll
            for (int k = 0; k < 3; ++k)
                xr_c[rt][k] = (row < N_EDGES) ? x[row * 3 + k] : 0.0f;
        }
    }
    __syncthreads();   // the ONLY barrier in the kernel

    // halved hnF bases (shorts): slot = kt_local*2+rt, 512 shorts/slot, wave-private.
    const int wbase = wave * 2048 + (q >> 1) * 128 + c * 8 + (q & 1) * 4;
    const int rbase = wave * 2048 + lane * 8;   // B-frag read base (lane-linear)
    const float4v zero4 = {0.0f, 0.0f, 0.0f, 0.0f};
    const float bo = b_out[0];
    const float4v* wo4 = (const float4v*)W_out;

    // ---- persistent group loop: ~30-31 groups per wg
    for (int grp = blockIdx.x; grp < NGRP2; grp += NWG) {
        const long rowbase = (long)grp * GRP_ROWS;

        // stage 1: h0[f][r] = W_in[f].x[r] + b_in[f], straight into D-layout regs
        float4v h[8][2];   // [ft][rt], component = reg
        #pragma unroll
        for (int ft = 0; ft < 8; ++ft)
            #pragma unroll
            for (int reg = 0; reg < 4; ++reg) {
                float4v wb = Win4[ft * 16 + q * 4 + reg];
                #pragma unroll
                for (int rt = 0; rt < 2; ++rt)
                    h[ft][rt][reg] = wb.w + xr_c[rt][0] * wb.x + xr_c[rt][1] * wb.y
                                          + xr_c[rt][2] * wb.z;
            }

        // prefetch next group's x (lands any time within this group's compute)
        if (grp + NWG < NGRP2) {
            long rb = rowbase + (long)NWG * GRP_ROWS;
            #pragma unroll
            for (int rt = 0; rt < 2; ++rt) {
                long row = rb + wave * 32 + rt * 16 + c;
                #pragma unroll
                for (int k = 0; k < 3; ++k)
                    xr_n[rt][k] = (row < N_EDGES) ? x[row * 3 + k] : 0.0f;
            }
        }

        float4v acc[8][2];
        ushort8 abuf3[2][8];   // blk3 global ping-pong (live blk2-end..blk3 only)

        // ---- residual blocks (NO barriers: hnF wave-private, W read-only/streamed)
        #pragma unroll
        for (int blk = 0; blk < NBLK; ++blk) {
            // write hn half0: ft=0..3 (frags for kt=0,1), 8 x ds_write_b64
            #pragma unroll
            for (int ft = 0; ft < 4; ++ft) {
                const int foff = ((ft >> 1) & 1) * 1024 + (ft & 1) * 256;
                #pragma unroll
                for (int rt = 0; rt < 2; ++rt) {
                    uint2v v;
                    v.x = pack_bf16(h[ft][rt][0], h[ft][rt][1]);
                    v.y = pack_bf16(h[ft][rt][2], h[ft][rt][3]);
                    *(uint2v*)&hnF[wbase + foff + rt * 512] = v;
                }
            }

            // rmsnorm scale per row: 4 partial sums, then xor over q
            float rs[2];
            #pragma unroll
            for (int rt = 0; rt < 2; ++rt) {
                float p0 = 0.0f, p1 = 0.0f, p2 = 0.0f, p3 = 0.0f;
                #pragma unroll
                for (int ft = 0; ft < 8; ++ft) {
                    p0 += h[ft][rt][0] * h[ft][rt][0];
                    p1 += h[ft][rt][1] * h[ft][rt][1];
                    p2 += h[ft][rt][2] * h[ft][rt][2];
                    p3 += h[ft][rt][3] * h[ft][rt][3];
                }
                float ss = (p0 + p1) + (p2 + p3);
                ss += __shfl_xor(ss, 16, 64);
                ss += __shfl_xor(ss, 32, 64);
                rs[rt] = rsqrtf(ss * (1.0f / 128.0f) + 1.1920929e-7f);
            }

            // read half0 B-frags (in-order DS => post-write data)
            bf16x8 bfr[4];
            #pragma unroll
            for (int i = 0; i < 4; ++i)
                bfr[i] = __builtin_bit_cast(bf16x8, *(const ushort8*)&hnF[rbase + i * 512]);

            if (blk == 2) {
                // prefetch blk3/kt0 from global -- covered by blk2 kt-chain + epilogue
                #pragma unroll
                for (int ft = 0; ft < 8; ++ft)
                    abuf3[0][ft] = *(const ushort8*)&WbF[49152 + ft * 512 + lane * 8];
            }
            if (blk == 3) {
                // prefetch kt1 into the other buffer before using kt0
                #pragma unroll
                for (int ft = 0; ft < 8; ++ft)
                    abuf3[1][ft] = *(const ushort8*)&WbF[49152 + 4096 + ft * 512 + lane * 8];
            }

            // MFMA kt = 0,1
            #pragma unroll
            for (int k2 = 0; k2 < 2; ++k2) {
                ushort8 a8[8];
                if (blk < 3) {
                    #pragma unroll
                    for (int ft = 0; ft < 8; ++ft)
                        a8[ft] = *(const ushort8*)&WsL[blk * 16384 + k2 * 4096
                                                       + ft * 512 + lane * 8];
                } else {
                    #pragma unroll
                    for (int ft = 0; ft < 8; ++ft) a8[ft] = abuf3[k2][ft];
                    if (k2 == 1) {
                        // prefetch kt2 into abuf3[0] (kt0 consumed)
                        #pragma unroll
                        for (int ft = 0; ft < 8; ++ft)
                            abuf3[0][ft] = *(const ushort8*)&WbF[49152 + 2 * 4096
                                                                 + ft * 512 + lane * 8];
                    }
                }
                bf16x8 b0 = bfr[k2 * 2 + 0];
                bf16x8 b1 = bfr[k2 * 2 + 1];
                __builtin_amdgcn_s_setprio(1);
                #pragma unroll
                for (int ft = 0; ft < 8; ++ft) {
                    bf16x8 a = __builtin_bit_cast(bf16x8, a8[ft]);
                    if (k2 == 0) {
                        acc[ft][0] = __builtin_amdgcn_mfma_f32_16x16x32_bf16(a, b0, zero4, 0, 0, 0);
                        acc[ft][1] = __builtin_amdgcn_mfma_f32_16x16x32_bf16(a, b1, zero4, 0, 0, 0);
                    } else {
                        acc[ft][0] = __builtin_amdgcn_mfma_f32_16x16x32_bf16(a, b0, acc[ft][0], 0, 0, 0);
                        acc[ft][1] = __builtin_amdgcn_mfma_f32_16x16x32_bf16(a, b1, acc[ft][1], 0, 0, 0);
                    }
                }
                __builtin_amdgcn_s_setprio(0);
            }

            // write hn half1: ft=4..7 into the SAME slots (in-order DS => WAR safe)
            #pragma unroll
            for (int ft = 4; ft < 8; ++ft) {
                const int foff = ((ft >> 1) & 1) * 1024 + (ft & 1) * 256;
                #pragma unroll
                for (int rt = 0; rt < 2; ++rt) {
                    uint2v v;
                    v.x = pack_bf16(h[ft][rt][0], h[ft][rt][1]);
                    v.y = pack_bf16(h[ft][rt][2], h[ft][rt][3]);
                    *(uint2v*)&hnF[wbase + foff + rt * 512] = v;
                }
            }
            // read half1 B-frags
            #pragma unroll
            for (int i = 0; i < 4; ++i)
                bfr[i] = __builtin_bit_cast(bf16x8, *(const ushort8*)&hnF[rbase + i * 512]);

            if (blk == 3) {
                // prefetch kt3 into abuf3[1] (kt1 consumed)
                #pragma unroll
                for (int ft = 0; ft < 8; ++ft)
                    abuf3[1][ft] = *(const ushort8*)&WbF[49152 + 3 * 4096
                                                         + ft * 512 + lane * 8];
            }

            // MFMA kt = 2,3
            #pragma unroll
            for (int k2 = 0; k2 < 2; ++k2) {
                ushort8 a8[8];
                if (blk < 3) {
                    #pragma unroll
                    for (int ft = 0; ft < 8; ++ft)
                        a8[ft] = *(const ushort8*)&WsL[blk * 16384 + (2 + k2) * 4096
                                                       + ft * 512 + lane * 8];
                } else {
                    #pragma unroll
                    for (int ft = 0; ft < 8; ++ft) a8[ft] = abuf3[k2][ft];
                }
                bf16x8 b0 = bfr[k2 * 2 + 0];
                bf16x8 b1 = bfr[k2 * 2 + 1];
                __builtin_amdgcn_s_setprio(1);
                #pragma unroll
                for (int ft = 0; ft < 8; ++ft) {
                    bf16x8 a = __builtin_bit_cast(bf16x8, a8[ft]);
                    acc[ft][0] = __builtin_amdgcn_mfma_f32_16x16x32_bf16(a, b0, acc[ft][0], 0, 0, 0);
                    acc[ft][1] = __builtin_amdgcn_mfma_f32_16x16x32_bf16(a, b1, acc[ft][1], 0, 0, 0);
                }
                __builtin_amdgcn_s_setprio(0);
            }

            // epilogue: h += relu(rs[rt]*acc + b_res[f])
            const float4v* br4 = (const float4v*)(b_res + blk * HID);
            #pragma unroll
            for (int ft = 0; ft < 8; ++ft) {
                float4v bb = br4[ft * 4 + q];
                #pragma unroll
                for (int rt = 0; rt < 2; ++rt) {
                    #pragma unroll
                    for (int reg = 0; reg < 4; ++reg)
                        h[ft][rt][reg] += fmaxf(fmaf(rs[rt], acc[ft][rt][reg], bb[reg]), 0.0f);
                }
            }
        }

        // output head: e[r] = exp(h[.][r] . W_out + b_out)
        float s2[2] = {0.0f, 0.0f};
        #pragma unroll
        for (int ft = 0; ft < 8; ++ft) {
            float4v w = wo4[ft * 4 + q];
            #pragma unroll
            for (int rt = 0; rt < 2; ++rt) {
                #pragma unroll
                for (int reg = 0; reg < 4; ++reg)
                    s2[rt] += h[ft][rt][reg] * w[reg];
            }
        }
        #pragma unroll
        for (int rt = 0; rt < 2; ++rt) {
            s2[rt] += __shfl_xor(s2[rt], 16, 64);
            s2[rt] += __shfl_xor(s2[rt], 32, 64);
        }
        if (q == 0) {
            #pragma unroll
            for (int rt = 0; rt < 2; ++rt) {
                long row = rowbase + wave * 32 + rt * 16 + c;
                if (row < N_EDGES) e[row] = __expf(s2[rt] + bo);
            }
        }

        // rotate the x pipeline
        #pragma unroll
        for (int rt = 0; rt < 2; ++rt)
            #pragma unroll
            for (int k = 0; k < 3; ++k)
                xr_c[rt][k] = xr_n[rt][k];
    }
}

// ---- segment sum of e (sorted ids): wave-level segmented scan, tail lanes atomicAdd
__global__ void segsum_kernel(const float* __restrict__ e, const int* __restrict__ ids,
                              float* __restrict__ segsum) {
    int i = blockIdx.x * 256 + threadIdx.x;
    int lane = threadIdx.x & 63;
    float v = 0.0f; int id = -1;
    if (i < N_EDGES) { v = e[i]; id = ids[i]; }
    #pragma unroll
    for (int d = 1; d < 64; d <<= 1) {
        float ov = __shfl_up(v, d, 64);
        int oid = __shfl_up(id, d, 64);
        if (lane >= d && oid == id) v += ov;
    }
    int nid = __shfl_down(id, 1, 64);
    bool tail = (lane == 63) || (nid != id);
    if (id >= 0 && tail) atomicAdd(&segsum[id], v);
}

__global__ void norm_kernel(const float* __restrict__ e, const int* __restrict__ ids,
                            const float* __restrict__ segsum, float* __restrict__ out) {
    int i = blockIdx.x * 256 + threadIdx.x;
    if (i < N_EDGES) out[i] = e[i] / segsum[ids[i]];
}

extern "C" void kernel_launch(void* const* d_in, const int* in_sizes, int n_in,
                              void* d_out, int out_size, void* d_ws, size_t ws_size,
                              hipStream_t stream) {
    const float* x      = (const float*)d_in[0];
    const int*   ids    = (const int*)d_in[1];
    const float* W_in   = (const float*)d_in[2];
    const float* b_in   = (const float*)d_in[3];
    const float* rms_w  = (const float*)d_in[4];
    const float* W_res  = (const float*)d_in[5];
    const float* b_res  = (const float*)d_in[6];
    const float* W_out  = (const float*)d_in[7];
    const float* b_out  = (const float*)d_in[8];
    float* out = (float*)d_out;

    char* ws = (char*)d_ws;
    unsigned short* WbF = (unsigned short*)ws;                 // 131072 B
    float* Win4   = (float*)(ws + 131072);                     // 2048 B
    float* e      = (float*)(ws + 131072 + 2048);              // 8,000,000 B
    float* segsum = (float*)(ws + 131072 + 2048 + 8000000);    // 2,000,000 B

    int prep_items = 65536 + 128 + NUM_SEG;
    prep_kernel<<<(prep_items + 255) / 256, 256, 0, stream>>>(W_res, rms_w, W_in, b_in,
                                                              WbF, Win4, segsum);
    mlp_kernel<<<NWG, 512, 0, stream>>>(x, WbF, b_res, W_out, b_out, Win4, e);
    segsum_kernel<<<(N_EDGES + 255) / 256, 256, 0, stream>>>(e, ids, segsum);
    norm_kernel<<<(N_EDGES + 255) / 256, 256, 0, stream>>>(e, ids, segsum, out);
}

// Round 13
// 811.564 us; speedup vs baseline: 1.1800x; 1.1800x over previous
//
#include <hip/hip_runtime.h>
#include <stdint.h>

#define N_EDGES 2000000
#define NUM_SEG 500000
#define HID 128
#define NBLK 4

typedef __attribute__((ext_vector_type(8))) unsigned short ushort8;
typedef __attribute__((ext_vector_type(8))) __bf16 bf16x8;
typedef __attribute__((ext_vector_type(4))) float float4v;
typedef __attribute__((ext_vector_type(2))) uint32_t uint2v;

__device__ inline unsigned short f32_to_bf16(float f) {
    return __builtin_bit_cast(unsigned short, (__bf16)f);   // native cvt, RNE
}

__device__ inline uint32_t pack_bf16(float lo, float hi) {
#if __has_builtin(__builtin_amdgcn_cvt_pk_bf16_f32)
    typedef __attribute__((ext_vector_type(2))) __bf16 bf16x2;
    bf16x2 r = __builtin_amdgcn_cvt_pk_bf16_f32(lo, hi);
    return __builtin_bit_cast(uint32_t, r);
#else
    return (uint32_t)f32_to_bf16(lo) | ((uint32_t)f32_to_bf16(hi) << 16);
#endif
}

// ---- prep: WbF[blk] = bf16(W_res*rms_w) in A-FRAGMENT ORDER:
//   i = blk*16384 + (kt*8+ft)*512 + lane*8 + j -> W'[m=ft*16+(lane&15)][k=kt*32+(lane>>4)*8+j]
// Also packs Win4[f] = {W_in[f][0..2], b_in[f]} and zero-fills segsum.
__global__ void prep_kernel(const float* __restrict__ W_res,
                            const float* __restrict__ rms_w,
                            const float* __restrict__ W_in,
                            const float* __restrict__ b_in,
                            unsigned short* __restrict__ WbF,
                            float* __restrict__ Win4,
                            float* __restrict__ segsum) {
    int i = blockIdx.x * 256 + threadIdx.x;
    if (i < 65536) {
        int blk = i >> 14;
        int r = i & 16383;
        int j = r & 7, lane = (r >> 3) & 63, ft = (r >> 9) & 7, kt = r >> 12;
        int cc = lane & 15, qq = lane >> 4;
        int row = ft * 16 + cc;
        int k = kt * 32 + qq * 8 + j;
        WbF[i] = f32_to_bf16(W_res[blk * 16384 + row * HID + k] * rms_w[blk * HID + k]);
    } else if (i < 65536 + 128) {
        int f = i - 65536;
        Win4[f * 4 + 0] = W_in[f * 3 + 0];
        Win4[f * 4 + 1] = W_in[f * 3 + 1];
        Win4[f * 4 + 2] = W_in[f * 3 + 2];
        Win4[f * 4 + 3] = b_in[f];
    } else {
        int s = i - 65536 - 128;
        if (s < NUM_SEG) segsum[s] = 0.0f;
    }
}

// ---- fused MLP: 128 rows/wg, 4 waves x 32 rows.
// R13 = R9's body (2-deep A-prefetch, 3-buffer rotation) with the register
// heuristic finally disarmed. Allocator map from R0-R12: with waves-per-eu slack
// the allocator TARGETS the 128-VGPR / 4-waves-per-EU tier and spills whatever
// doesn't fit (R9: needed ~160 -> 128+365MB scratch; R12: needed ~200 -> same).
// amdgpu_waves_per_eu(2,2) pins BOTH bounds: min=2 avoids the R4 residency
// collapse, max=2 removes the 4/EU target -> budget 512/2 = 256 regs, so R9's
// ~160-200 live set allocates cleanly. R12 also showed A-from-LDS saturates the
// DS pipe at 8 waves -> A stays on the L2 path (DS pipe reserved for hn).
// Decisive signature: VGPR 150-200 + FETCH ~12.3 MB = experiment finally runs;
// VGPR 128 + FETCH balloon = attribute ignored, toolchain closed, R8 stands.
__launch_bounds__(256)
__attribute__((amdgpu_waves_per_eu(2, 2)))
__global__ void mlp_kernel(const float* __restrict__ x,           // [N,3]
                           const unsigned short* __restrict__ WbF,// [4,16384] bf16 A-frag order
                           const float* __restrict__ b_res,       // [4,128]
                           const float* __restrict__ W_out,       // [128]
                           const float* __restrict__ b_out,       // [1]
                           const float* __restrict__ Win4g,       // [128,4] = {w0,w1,w2,b_in}
                           float* __restrict__ e) {               // [N] = exp(logit)
    __shared__ __align__(16) unsigned short hnF[16384];   // 32 KB, B-frag order (8KB/wave)
    __shared__ __align__(16) float4v Win4[128];
    __shared__ float xs[384];

    const int t = threadIdx.x;
    const int wave = t >> 6;
    const int lane = t & 63;
    const int q = lane >> 4;   // quad within wave
    const int c = lane & 15;   // lane within quad
    const long rowbase = (long)blockIdx.x * 128;

    // A-frag rotation buffers; prologue: steps 0 (blk0/kt0) and 1 (blk0/kt1)
    ushort8 abuf[3][8];
    #pragma unroll
    for (int ft = 0; ft < 8; ++ft)
        abuf[0][ft] = *(const ushort8*)&WbF[0 * 4096 + ft * 512 + lane * 8];
    #pragma unroll
    for (int ft = 0; ft < 8; ++ft)
        abuf[1][ft] = *(const ushort8*)&WbF[1 * 4096 + ft * 512 + lane * 8];

    for (int i = t; i < 384; i += 256) xs[i] = x[rowbase * 3 + i];
    if (t < 128) Win4[t] = ((const float4v*)Win4g)[t];
    __syncthreads();   // the ONLY block-wide barrier in this kernel

    // ---- stage 1: h0[f][r] = W_in[f].x[r] + b_in[f], straight into D-layout regs
    float4v h[8][2];   // [ft][rt], component = reg
    {
        float xr[2][3];
        #pragma unroll
        for (int rt = 0; rt < 2; ++rt)
            #pragma unroll
            for (int k = 0; k < 3; ++k)
                xr[rt][k] = xs[(wave * 32 + rt * 16 + c) * 3 + k];
        #pragma unroll
        for (int ft = 0; ft < 8; ++ft)
            #pragma unroll
            for (int reg = 0; reg < 4; ++reg) {
                float4v wb = Win4[ft * 16 + q * 4 + reg];
                #pragma unroll
                for (int rt = 0; rt < 2; ++rt)
                    h[ft][rt][reg] = wb.w + xr[rt][0] * wb.x + xr[rt][1] * wb.y + xr[rt][2] * wb.z;
            }
    }

    // hnF bases (shorts), R0 full layout: slot (kt=ft>>1)*2+rt, 512 shorts/slot, wave-private.
    const int wbase = wave * 4096 + (q >> 1) * 128 + c * 8 + (q & 1) * 4;
    const int rbase = wave * 4096 + lane * 8;   // B-frag read base (lane-linear)
    const float4v zero4 = {0.0f, 0.0f, 0.0f, 0.0f};

    float4v acc[8][2];

    // ---- residual blocks (NO barriers: hnF wave-private, W from global/L2)
    #pragma unroll
    for (int blk = 0; blk < NBLK; ++blk) {
        // write h as packed bf16 into B-frag-order LDS (16 x ds_write_b64)
        #pragma unroll
        for (int ft = 0; ft < 8; ++ft) {
            const int foff = (ft >> 1) * 1024 + (ft & 1) * 256;
            #pragma unroll
            for (int rt = 0; rt < 2; ++rt) {
                uint2v v;
                v.x = pack_bf16(h[ft][rt][0], h[ft][rt][1]);
                v.y = pack_bf16(h[ft][rt][2], h[ft][rt][3]);
                *(uint2v*)&hnF[wbase + foff + rt * 512] = v;
            }
        }

        // hoist ALL 8 B-fragment reads (in-order DS pipe => reads return post-write
        // data; results land under the rmsnorm VALU)
        bf16x8 bfr[8];
        #pragma unroll
        for (int i = 0; i < 8; ++i)
            bfr[i] = __builtin_bit_cast(bf16x8, *(const ushort8*)&hnF[rbase + i * 512]);

        // rmsnorm scale per row: 4 partial sums (dep chain 8 FMA), then xor over q
        float rs[2];
        #pragma unroll
        for (int rt = 0; rt < 2; ++rt) {
            float p0 = 0.0f, p1 = 0.0f, p2 = 0.0f, p3 = 0.0f;
            #pragma unroll
            for (int ft = 0; ft < 8; ++ft) {
                p0 += h[ft][rt][0] * h[ft][rt][0];
                p1 += h[ft][rt][1] * h[ft][rt][1];
                p2 += h[ft][rt][2] * h[ft][rt][2];
                p3 += h[ft][rt][3] * h[ft][rt][3];
            }
            float ss = (p0 + p1) + (p2 + p3);
            ss += __shfl_xor(ss, 16, 64);
            ss += __shfl_xor(ss, 32, 64);
            rs[rt] = rsqrtf(ss * (1.0f / 128.0f) + 1.1920929e-7f);
        }

        // kt clusters with 2-deep rotation: global step s = blk*4+kt;
        // use abuf[s%3]; prefetch data for step s+2 into abuf[(s+2)%3]
        // (that buffer's last use was cluster s-1 -- free). Indices are
        // compile-time constants after full unroll.
        #pragma unroll
        for (int kt = 0; kt < 4; ++kt) {
            const int s = blk * 4 + kt;
            const int cur = s % 3;
            const int pre = (s + 2) % 3;
            const int ps = s + 2;   // data step being prefetched
            if (ps < NBLK * 4) {
                const unsigned short* pn = WbF + (ps >> 2) * 16384 + (ps & 3) * 4096;
                #pragma unroll
                for (int ft = 0; ft < 8; ++ft)
                    abuf[pre][ft] = *(const ushort8*)&pn[ft * 512 + lane * 8];
            }
            bf16x8 b0 = bfr[kt * 2 + 0];
            bf16x8 b1 = bfr[kt * 2 + 1];
            __builtin_amdgcn_s_setprio(1);
            #pragma unroll
            for (int ft = 0; ft < 8; ++ft) {
                bf16x8 a = __builtin_bit_cast(bf16x8, abuf[cur][ft]);
                if (kt == 0) {
                    acc[ft][0] = __builtin_amdgcn_mfma_f32_16x16x32_bf16(a, b0, zero4, 0, 0, 0);
                    acc[ft][1] = __builtin_amdgcn_mfma_f32_16x16x32_bf16(a, b1, zero4, 0, 0, 0);
                } else {
                    acc[ft][0] = __builtin_amdgcn_mfma_f32_16x16x32_bf16(a, b0, acc[ft][0], 0, 0, 0);
                    acc[ft][1] = __builtin_amdgcn_mfma_f32_16x16x32_bf16(a, b1, acc[ft][1], 0, 0, 0);
                }
            }
            __builtin_amdgcn_s_setprio(0);
        }

        // epilogue: h += relu(rs[rt]*acc + b_res[f])
        const float4v* br4 = (const float4v*)(b_res + blk * HID);
        #pragma unroll
        for (int ft = 0; ft < 8; ++ft) {
            float4v bb = br4[ft * 4 + q];
            #pragma unroll
            for (int rt = 0; rt < 2; ++rt) {
                #pragma unroll
                for (int reg = 0; reg < 4; ++reg)
                    h[ft][rt][reg] += fmaxf(fmaf(rs[rt], acc[ft][rt][reg], bb[reg]), 0.0f);
            }
        }
    }

    // ---- output head: e[r] = exp(h[.][r] . W_out + b_out)
    const float bo = b_out[0];
    const float4v* wo4 = (const float4v*)W_out;
    float s2[2] = {0.0f, 0.0f};
    #pragma unroll
    for (int ft = 0; ft < 8; ++ft) {
        float4v w = wo4[ft * 4 + q];
        #pragma unroll
        for (int rt = 0; rt < 2; ++rt) {
            #pragma unroll
            for (int reg = 0; reg < 4; ++reg)
                s2[rt] += h[ft][rt][reg] * w[reg];
        }
    }
    #pragma unroll
    for (int rt = 0; rt < 2; ++rt) {
        s2[rt] += __shfl_xor(s2[rt], 16, 64);
        s2[rt] += __shfl_xor(s2[rt], 32, 64);
    }
    if (q == 0) {
        #pragma unroll
        for (int rt = 0; rt < 2; ++rt)
            e[rowbase + wave * 32 + rt * 16 + c] = __expf(s2[rt] + bo);
    }
}

// ---- segment sum of e (sorted ids): wave-level segmented scan, tail lanes atomicAdd
__global__ void segsum_kernel(const float* __restrict__ e, const int* __restrict__ ids,
                              float* __restrict__ segsum) {
    int i = blockIdx.x * 256 + threadIdx.x;
    int lane = threadIdx.x & 63;
    float v = 0.0f; int id = -1;
    if (i < N_EDGES) { v = e[i]; id = ids[i]; }
    #pragma unroll
    for (int d = 1; d < 64; d <<= 1) {
        float ov = __shfl_up(v, d, 64);
        int oid = __shfl_up(id, d, 64);
        if (lane >= d && oid == id) v += ov;
    }
    int nid = __shfl_down(id, 1, 64);
    bool tail = (lane == 63) || (nid != id);
    if (id >= 0 && tail) atomicAdd(&segsum[id], v);
}

__global__ void norm_kernel(const float* __restrict__ e, const int* __restrict__ ids,
                            const float* __restrict__ segsum, float* __restrict__ out) {
    int i = blockIdx.x * 256 + threadIdx.x;
    if (i < N_EDGES) out[i] = e[i] / segsum[ids[i]];
}

extern "C" void kernel_launch(void* const* d_in, const int* in_sizes, int n_in,
                              void* d_out, int out_size, void* d_ws, size_t ws_size,
                              hipStream_t stream) {
    const float* x      = (const float*)d_in[0];
    const int*   ids    = (const int*)d_in[1];
    const float* W_in   = (const float*)d_in[2];
    const float* b_in   = (const float*)d_in[3];
    const float* rms_w  = (const float*)d_in[4];
    const float* W_res  = (const float*)d_in[5];
    const float* b_res  = (const float*)d_in[6];
    const float* W_out  = (const float*)d_in[7];
    const float* b_out  = (const float*)d_in[8];
    float* out = (float*)d_out;

    char* ws = (char*)d_ws;
    unsigned short* WbF = (unsigned short*)ws;                 // 131072 B
    float* Win4   = (float*)(ws + 131072);                     // 2048 B
    float* e      = (float*)(ws + 131072 + 2048);              // 8,000,000 B
    float* segsum = (float*)(ws + 131072 + 2048 + 8000000);    // 2,000,000 B

    int prep_items = 65536 + 128 + NUM_SEG;
    prep_kernel<<<(prep_items + 255) / 256, 256, 0, stream>>>(W_res, rms_w, W_in, b_in,
                                                              WbF, Win4, segsum);
    mlp_kernel<<<N_EDGES / 128, 256, 0, stream>>>(x, WbF, b_res, W_out, b_out, Win4, e);
    segsum_kernel<<<(N_EDGES + 255) / 256, 256, 0, stream>>>(e, ids, segsum);
    norm_kernel<<<(N_EDGES + 255) / 256, 256, 0, stream>>>(e, ids, segsum, out);
}

// Round 15
// 710.323 us; speedup vs baseline: 1.3482x; 1.1425x over previous
//
#include <hip/hip_runtime.h>
#include <stdint.h>

#define N_EDGES 2000000
#define NUM_SEG 500000
#define HID 128
#define NBLK 4

typedef __attribute__((ext_vector_type(8))) unsigned short ushort8;
typedef __attribute__((ext_vector_type(8))) __bf16 bf16x8;
typedef __attribute__((ext_vector_type(4))) float float4v;
typedef __attribute__((ext_vector_type(2))) uint32_t uint2v;

__device__ inline unsigned short f32_to_bf16(float f) {
    return __builtin_bit_cast(unsigned short, (__bf16)f);   // native cvt, RNE
}

__device__ inline uint32_t pack_bf16(float lo, float hi) {
#if __has_builtin(__builtin_amdgcn_cvt_pk_bf16_f32)
    typedef __attribute__((ext_vector_type(2))) __bf16 bf16x2;
    bf16x2 r = __builtin_amdgcn_cvt_pk_bf16_f32(lo, hi);
    return __builtin_bit_cast(uint32_t, r);
#else
    return (uint32_t)f32_to_bf16(lo) | ((uint32_t)f32_to_bf16(hi) << 16);
#endif
}

// ---- prep: WbF[blk] = bf16(W_res*rms_w) in A-FRAGMENT ORDER:
//   i = blk*16384 + (kt*8+ft)*512 + lane*8 + j -> W'[m=ft*16+(lane&15)][k=kt*32+(lane>>4)*8+j]
// Also packs Win4[f] = {W_in[f][0..2], b_in[f]} and zero-fills segsum.
__global__ void prep_kernel(const float* __restrict__ W_res,
                            const float* __restrict__ rms_w,
                            const float* __restrict__ W_in,
                            const float* __restrict__ b_in,
                            unsigned short* __restrict__ WbF,
                            float* __restrict__ Win4,
                            float* __restrict__ segsum) {
    int i = blockIdx.x * 256 + threadIdx.x;
    if (i < 65536) {
        int blk = i >> 14;
        int r = i & 16383;
        int j = r & 7, lane = (r >> 3) & 63, ft = (r >> 9) & 7, kt = r >> 12;
        int cc = lane & 15, qq = lane >> 4;
        int row = ft * 16 + cc;
        int k = kt * 32 + qq * 8 + j;
        WbF[i] = f32_to_bf16(W_res[blk * 16384 + row * HID + k] * rms_w[blk * HID + k]);
    } else if (i < 65536 + 128) {
        int f = i - 65536;
        Win4[f * 4 + 0] = W_in[f * 3 + 0];
        Win4[f * 4 + 1] = W_in[f * 3 + 1];
        Win4[f * 4 + 2] = W_in[f * 3 + 2];
        Win4[f * 4 + 3] = b_in[f];
    } else {
        int s = i - 65536 - 128;
        if (s < NUM_SEG) segsum[s] = 0.0f;
    }
}

// ---- fused MLP: 128 rows/wg, 4 waves x 32 rows.
// R15 = RETRY of R14 (core-dumped with no kernel error -- full address audit
// found every LDS/global access in-bounds; LDS total and launch_bounds are
// exactly R0's proven config; body is R9's harness-run code + in-bounds hoff.
// Classified as transient node fault; pre-commit: crashes again => config is
// deterministically toxic => revert to R8 and declare).
// Experiment: R9's 2-deep A-prefetch with the register budget bought via LDS.
// Allocator model (R0-R13): reg cap = 512 / (LDS-implied waves/EU):
//   LDS 32-36K -> cap 128 (R8=124 clean; R9/R13 needed ~160 -> spill)
//   LDS 69K    -> cap 256 (R0=120 clean)
//   LDS 133K   -> cap 512 (R10=256 clean)
// hnF double-buffered per block (2 x 32 KB, blk&1) pads LDS to 69,120 B ->
// 2 wgs/CU -> cap 256 -> ~160-200-reg live set allocates cleanly. Occupancy
// stays 2 waves/EU (R8's regime) -- isolates prefetch depth.
// Decisive signature: VGPR 150-200 + FETCH ~12.3 MB = experiment runs;
// VGPR 128 + balloon = unconditional cap, toolchain closed, R8 stands.
__launch_bounds__(256, 2)
__global__ void mlp_kernel(const float* __restrict__ x,           // [N,3]
                           const unsigned short* __restrict__ WbF,// [4,16384] bf16 A-frag order
                           const float* __restrict__ b_res,       // [4,128]
                           const float* __restrict__ W_out,       // [128]
                           const float* __restrict__ b_out,       // [1]
                           const float* __restrict__ Win4g,       // [128,4] = {w0,w1,w2,b_in}
                           float* __restrict__ e) {               // [N] = exp(logit)
    __shared__ __align__(16) unsigned short hnF[32768];   // 64 KB: 2 x B-frag buffers (blk&1)
    __shared__ __align__(16) float4v Win4[128];           // 2 KB
    __shared__ float xs[384];                             // 1.5 KB   => total 69,120 B

    const int t = threadIdx.x;
    const int wave = t >> 6;
    const int lane = t & 63;
    const int q = lane >> 4;   // quad within wave
    const int c = lane & 15;   // lane within quad
    const long rowbase = (long)blockIdx.x * 128;

    // A-frag rotation buffers; prologue: steps 0 (blk0/kt0) and 1 (blk0/kt1)
    ushort8 abuf[3][8];
    #pragma unroll
    for (int ft = 0; ft < 8; ++ft)
        abuf[0][ft] = *(const ushort8*)&WbF[0 * 4096 + ft * 512 + lane * 8];
    #pragma unroll
    for (int ft = 0; ft < 8; ++ft)
        abuf[1][ft] = *(const ushort8*)&WbF[1 * 4096 + ft * 512 + lane * 8];

    for (int i = t; i < 384; i += 256) xs[i] = x[rowbase * 3 + i];
    if (t < 128) Win4[t] = ((const float4v*)Win4g)[t];
    __syncthreads();   // the ONLY block-wide barrier in this kernel

    // ---- stage 1: h0[f][r] = W_in[f].x[r] + b_in[f], straight into D-layout regs
    float4v h[8][2];   // [ft][rt], component = reg
    {
        float xr[2][3];
        #pragma unroll
        for (int rt = 0; rt < 2; ++rt)
            #pragma unroll
            for (int k = 0; k < 3; ++k)
                xr[rt][k] = xs[(wave * 32 + rt * 16 + c) * 3 + k];
        #pragma unroll
        for (int ft = 0; ft < 8; ++ft)
            #pragma unroll
            for (int reg = 0; reg < 4; ++reg) {
                float4v wb = Win4[ft * 16 + q * 4 + reg];
                #pragma unroll
                for (int rt = 0; rt < 2; ++rt)
                    h[ft][rt][reg] = wb.w + xr[rt][0] * wb.x + xr[rt][1] * wb.y + xr[rt][2] * wb.z;
            }
    }

    // hnF bases (shorts), R0 layout: slot (kt=ft>>1)*2+rt, 512 shorts/slot, wave-private.
    // Per-block buffer alternation adds hoff = (blk&1)*16384.
    const int wbase = wave * 4096 + (q >> 1) * 128 + c * 8 + (q & 1) * 4;
    const int rbase = wave * 4096 + lane * 8;   // B-frag read base (lane-linear)
    const float4v zero4 = {0.0f, 0.0f, 0.0f, 0.0f};

    float4v acc[8][2];

    // ---- residual blocks (NO barriers: hnF wave-private, W from global/L2)
    #pragma unroll
    for (int blk = 0; blk < NBLK; ++blk) {
        const int hoff = (blk & 1) * 16384;   // compile-time after unroll

        // write h as packed bf16 into B-frag-order LDS (16 x ds_write_b64)
        #pragma unroll
        for (int ft = 0; ft < 8; ++ft) {
            const int foff = (ft >> 1) * 1024 + (ft & 1) * 256;
            #pragma unroll
            for (int rt = 0; rt < 2; ++rt) {
                uint2v v;
                v.x = pack_bf16(h[ft][rt][0], h[ft][rt][1]);
                v.y = pack_bf16(h[ft][rt][2], h[ft][rt][3]);
                *(uint2v*)&hnF[hoff + wbase + foff + rt * 512] = v;
            }
        }

        // hoist ALL 8 B-fragment reads (in-order DS pipe => reads return post-write
        // data; results land under the rmsnorm VALU)
        bf16x8 bfr[8];
        #pragma unroll
        for (int i = 0; i < 8; ++i)
            bfr[i] = __builtin_bit_cast(bf16x8,
                        *(const ushort8*)&hnF[hoff + rbase + i * 512]);

        // rmsnorm scale per row: 4 partial sums (dep chain 8 FMA), then xor over q
        float rs[2];
        #pragma unroll
        for (int rt = 0; rt < 2; ++rt) {
            float p0 = 0.0f, p1 = 0.0f, p2 = 0.0f, p3 = 0.0f;
            #pragma unroll
            for (int ft = 0; ft < 8; ++ft) {
                p0 += h[ft][rt][0] * h[ft][rt][0];
                p1 += h[ft][rt][1] * h[ft][rt][1];
                p2 += h[ft][rt][2] * h[ft][rt][2];
                p3 += h[ft][rt][3] * h[ft][rt][3];
            }
            float ss = (p0 + p1) + (p2 + p3);
            ss += __shfl_xor(ss, 16, 64);
            ss += __shfl_xor(ss, 32, 64);
            rs[rt] = rsqrtf(ss * (1.0f / 128.0f) + 1.1920929e-7f);
        }

        // kt clusters with 2-deep rotation: global step s = blk*4+kt;
        // use abuf[s%3]; prefetch data for step s+2 into abuf[(s+2)%3]
        // (that buffer's last use was cluster s-1 -- free). Indices are
        // compile-time constants after full unroll.
        #pragma unroll
        for (int kt = 0; kt < 4; ++kt) {
            const int s = blk * 4 + kt;
            const int cur = s % 3;
            const int pre = (s + 2) % 3;
            const int ps = s + 2;   // data step being prefetched
            if (ps < NBLK * 4) {
                const unsigned short* pn = WbF + (ps >> 2) * 16384 + (ps & 3) * 4096;
                #pragma unroll
                for (int ft = 0; ft < 8; ++ft)
                    abuf[pre][ft] = *(const ushort8*)&pn[ft * 512 + lane * 8];
            }
            bf16x8 b0 = bfr[kt * 2 + 0];
            bf16x8 b1 = bfr[kt * 2 + 1];
            __builtin_amdgcn_s_setprio(1);
            #pragma unroll
            for (int ft = 0; ft < 8; ++ft) {
                bf16x8 a = __builtin_bit_cast(bf16x8, abuf[cur][ft]);
                if (kt == 0) {
                    acc[ft][0] = __builtin_amdgcn_mfma_f32_16x16x32_bf16(a, b0, zero4, 0, 0, 0);
                    acc[ft][1] = __builtin_amdgcn_mfma_f32_16x16x32_bf16(a, b1, zero4, 0, 0, 0);
                } else {
                    acc[ft][0] = __builtin_amdgcn_mfma_f32_16x16x32_bf16(a, b0, acc[ft][0], 0, 0, 0);
                    acc[ft][1] = __builtin_amdgcn_mfma_f32_16x16x32_bf16(a, b1, acc[ft][1], 0, 0, 0);
                }
            }
            __builtin_amdgcn_s_setprio(0);
        }

        // epilogue: h += relu(rs[rt]*acc + b_res[f])
        const float4v* br4 = (const float4v*)(b_res + blk * HID);
        #pragma unroll
        for (int ft = 0; ft < 8; ++ft) {
            float4v bb = br4[ft * 4 + q];
            #pragma unroll
            for (int rt = 0; rt < 2; ++rt) {
                #pragma unroll
                for (int reg = 0; reg < 4; ++reg)
                    h[ft][rt][reg] += fmaxf(fmaf(rs[rt], acc[ft][rt][reg], bb[reg]), 0.0f);
            }
        }
    }

    // ---- output head: e[r] = exp(h[.][r] . W_out + b_out)
    const float bo = b_out[0];
    const float4v* wo4 = (const float4v*)W_out;
    float s2[2] = {0.0f, 0.0f};
    #pragma unroll
    for (int ft = 0; ft < 8; ++ft) {
        float4v w = wo4[ft * 4 + q];
        #pragma unroll
        for (int rt = 0; rt < 2; ++rt) {
            #pragma unroll
            for (int reg = 0; reg < 4; ++reg)
                s2[rt] += h[ft][rt][reg] * w[reg];
        }
    }
    #pragma unroll
    for (int rt = 0; rt < 2; ++rt) {
        s2[rt] += __shfl_xor(s2[rt], 16, 64);
        s2[rt] += __shfl_xor(s2[rt], 32, 64);
    }
    if (q == 0) {
        #pragma unroll
        for (int rt = 0; rt < 2; ++rt)
            e[rowbase + wave * 32 + rt * 16 + c] = __expf(s2[rt] + bo);
    }
}

// ---- segment sum of e (sorted ids): wave-level segmented scan, tail lanes atomicAdd
__global__ void segsum_kernel(const float* __restrict__ e, const int* __restrict__ ids,
                              float* __restrict__ segsum) {
    int i = blockIdx.x * 256 + threadIdx.x;
    int lane = threadIdx.x & 63;
    float v = 0.0f; int id = -1;
    if (i < N_EDGES) { v = e[i]; id = ids[i]; }
    #pragma unroll
    for (int d = 1; d < 64; d <<= 1) {
        float ov = __shfl_up(v, d, 64);
        int oid = __shfl_up(id, d, 64);
        if (lane >= d && oid == id) v += ov;
    }
    int nid = __shfl_down(id, 1, 64);
    bool tail = (lane == 63) || (nid != id);
    if (id >= 0 && tail) atomicAdd(&segsum[id], v);
}

__global__ void norm_kernel(const float* __restrict__ e, const int* __restrict__ ids,
                            const float* __restrict__ segsum, float* __restrict__ out) {
    int i = blockIdx.x * 256 + threadIdx.x;
    if (i < N_EDGES) out[i] = e[i] / segsum[ids[i]];
}

extern "C" void kernel_launch(void* const* d_in, const int* in_sizes, int n_in,
                              void* d_out, int out_size, void* d_ws, size_t ws_size,
                              hipStream_t stream) {
    const float* x      = (const float*)d_in[0];
    const int*   ids    = (const int*)d_in[1];
    const float* W_in   = (const float*)d_in[2];
    const float* b_in   = (const float*)d_in[3];
    const float* rms_w  = (const float*)d_in[4];
    const float* W_res  = (const float*)d_in[5];
    const float* b_res  = (const float*)d_in[6];
    const float* W_out  = (const float*)d_in[7];
    const float* b_out  = (const float*)d_in[8];
    float* out = (float*)d_out;

    char* ws = (char*)d_ws;
    unsigned short* WbF = (unsigned short*)ws;                 // 131072 B
    float* Win4   = (float*)(ws + 131072);                     // 2048 B
    float* e      = (float*)(ws + 131072 + 2048);              // 8,000,000 B
    float* segsum = (float*)(ws + 131072 + 2048 + 8000000);    // 2,000,000 B

    int prep_items = 65536 + 128 + NUM_SEG;
    prep_kernel<<<(prep_items + 255) / 256, 256, 0, stream>>>(W_res, rms_w, W_in, b_in,
                                                              WbF, Win4, segsum);
    mlp_kernel<<<N_EDGES / 128, 256, 0, stream>>>(x, WbF, b_res, W_out, b_out, Win4, e);
    segsum_kernel<<<(N_EDGES + 255) / 256, 256, 0, stream>>>(e, ids, segsum);
    norm_kernel<<<(N_EDGES + 255) / 256, 256, 0, stream>>>(e, ids, segsum, out);
}

// Round 16
// 492.455 us; speedup vs baseline: 1.9447x; 1.4424x over previous
//
#include <hip/hip_runtime.h>
#include <stdint.h>

#define N_EDGES 2000000
#define NUM_SEG 500000
#define HID 128
#define NBLK 4

typedef __attribute__((ext_vector_type(8))) unsigned short ushort8;
typedef __attribute__((ext_vector_type(8))) __bf16 bf16x8;
typedef __attribute__((ext_vector_type(4))) float float4v;
typedef __attribute__((ext_vector_type(2))) uint32_t uint2v;

__device__ inline unsigned short f32_to_bf16(float f) {
    return __builtin_bit_cast(unsigned short, (__bf16)f);   // native cvt, RNE
}

__device__ inline uint32_t pack_bf16(float lo, float hi) {
#if __has_builtin(__builtin_amdgcn_cvt_pk_bf16_f32)
    typedef __attribute__((ext_vector_type(2))) __bf16 bf16x2;
    bf16x2 r = __builtin_amdgcn_cvt_pk_bf16_f32(lo, hi);
    return __builtin_bit_cast(uint32_t, r);
#else
    return (uint32_t)f32_to_bf16(lo) | ((uint32_t)f32_to_bf16(hi) << 16);
#endif
}

// ---- prep: WbF[blk] = bf16(W_res*rms_w) in A-FRAGMENT ORDER:
//   i = blk*16384 + (kt*8+ft)*512 + lane*8 + j -> W'[m=ft*16+(lane&15)][k=kt*32+(lane>>4)*8+j]
// Also packs Win4[f] = {W_in[f][0..2], b_in[f]} and zero-fills segsum.
__global__ void prep_kernel(const float* __restrict__ W_res,
                            const float* __restrict__ rms_w,
                            const float* __restrict__ W_in,
                            const float* __restrict__ b_in,
                            unsigned short* __restrict__ WbF,
                            float* __restrict__ Win4,
                            float* __restrict__ segsum) {
    int i = blockIdx.x * 256 + threadIdx.x;
    if (i < 65536) {
        int blk = i >> 14;
        int r = i & 16383;
        int j = r & 7, lane = (r >> 3) & 63, ft = (r >> 9) & 7, kt = r >> 12;
        int cc = lane & 15, qq = lane >> 4;
        int row = ft * 16 + cc;
        int k = kt * 32 + qq * 8 + j;
        WbF[i] = f32_to_bf16(W_res[blk * 16384 + row * HID + k] * rms_w[blk * HID + k]);
    } else if (i < 65536 + 128) {
        int f = i - 65536;
        Win4[f * 4 + 0] = W_in[f * 3 + 0];
        Win4[f * 4 + 1] = W_in[f * 3 + 1];
        Win4[f * 4 + 2] = W_in[f * 3 + 2];
        Win4[f * 4 + 3] = b_in[f];
    } else {
        int s = i - 65536 - 128;
        if (s < NUM_SEG) segsum[s] = 0.0f;
    }
}

// ---- fused MLP: 128 rows/wg, 4 waves x 32 rows.
// R16 = REVERT to R8, the session's best verified kernel (474 us mlp, 488 total;
// matched-prediction win: exposed-latency reduction via hoisted B-frag reads +
// setprio + widened rmsnorm). Session conclusion after R9-R15: the remaining
// stall is queued-L2 A-fragment latency; covering it needs prefetch depth that
// requires >128 arch VGPRs at 2 waves/EU, and this toolchain's allocator caps
// arch VGPRs at 128 for ANY multi-wave-resident config (attributes, LDS tiers,
// and wg geometry all tested and failed: R13 attr ignored; R15 69KB-LDS still
// 128+spill; R12 512-thread 1-wg still 128+spill). The only 256-reg allocation
// (R10, 1 wave/EU) halves wave count and nets slower. R8 is the plateau of this
// structure on this toolchain.
__launch_bounds__(256, 2)
__global__ void mlp_kernel(const float* __restrict__ x,           // [N,3]
                           const unsigned short* __restrict__ WbF,// [4,16384] bf16 A-frag order
                           const float* __restrict__ b_res,       // [4,128]
                           const float* __restrict__ W_out,       // [128]
                           const float* __restrict__ b_out,       // [1]
                           const float* __restrict__ Win4g,       // [128,4] = {w0,w1,w2,b_in}
                           float* __restrict__ e) {               // [N] = exp(logit)
    __shared__ __align__(16) unsigned short hnF[16384];   // 32 KB, B-frag order (8KB/wave)
    __shared__ __align__(16) float4v Win4[128];
    __shared__ float xs[384];

    const int t = threadIdx.x;
    const int wave = t >> 6;
    const int lane = t & 63;
    const int q = lane >> 4;   // quad within wave
    const int c = lane & 15;   // lane within quad
    const long rowbase = (long)blockIdx.x * 128;

    // A-frag ping-pong buffers; preload blk0/kt0 (8 x global dwordx4, L2-hot)
    ushort8 a0[8], a1[8];
    #pragma unroll
    for (int ft = 0; ft < 8; ++ft)
        a0[ft] = *(const ushort8*)&WbF[ft * 512 + lane * 8];

    for (int i = t; i < 384; i += 256) xs[i] = x[rowbase * 3 + i];
    if (t < 128) Win4[t] = ((const float4v*)Win4g)[t];
    __syncthreads();   // the ONLY block-wide barrier in this kernel

    // ---- stage 1: h0[f][r] = W_in[f].x[r] + b_in[f], straight into D-layout regs
    float4v h[8][2];   // [ft][rt], component = reg
    {
        float xr[2][3];
        #pragma unroll
        for (int rt = 0; rt < 2; ++rt)
            #pragma unroll
            for (int k = 0; k < 3; ++k)
                xr[rt][k] = xs[(wave * 32 + rt * 16 + c) * 3 + k];
        #pragma unroll
        for (int ft = 0; ft < 8; ++ft)
            #pragma unroll
            for (int reg = 0; reg < 4; ++reg) {
                float4v wb = Win4[ft * 16 + q * 4 + reg];
                #pragma unroll
                for (int rt = 0; rt < 2; ++rt)
                    h[ft][rt][reg] = wb.w + xr[rt][0] * wb.x + xr[rt][1] * wb.y + xr[rt][2] * wb.z;
            }
    }

    // hnF bases (shorts), R0 full layout: slot (kt=ft>>1)*2+rt, 512 shorts/slot, wave-private.
    const int wbase = wave * 4096 + (q >> 1) * 128 + c * 8 + (q & 1) * 4;
    const int rbase = wave * 4096 + lane * 8;   // B-frag read base (lane-linear)
    const float4v zero4 = {0.0f, 0.0f, 0.0f, 0.0f};

    float4v acc[8][2];

    // one kt-step: prefetch next kt's A-frags from global, then 16 MFMA on preloaded B
    auto ktstep = [&](ushort8 (&ac)[8], ushort8 (&an)[8], bf16x8 b0, bf16x8 b1,
                      const unsigned short* pn, bool first) {
        if (pn) {
            #pragma unroll
            for (int ft = 0; ft < 8; ++ft)
                an[ft] = *(const ushort8*)&pn[ft * 512 + lane * 8];
        }
        __builtin_amdgcn_s_setprio(1);
        #pragma unroll
        for (int ft = 0; ft < 8; ++ft) {
            bf16x8 a = __builtin_bit_cast(bf16x8, ac[ft]);
            if (first) {
                acc[ft][0] = __builtin_amdgcn_mfma_f32_16x16x32_bf16(a, b0, zero4, 0, 0, 0);
                acc[ft][1] = __builtin_amdgcn_mfma_f32_16x16x32_bf16(a, b1, zero4, 0, 0, 0);
            } else {
                acc[ft][0] = __builtin_amdgcn_mfma_f32_16x16x32_bf16(a, b0, acc[ft][0], 0, 0, 0);
                acc[ft][1] = __builtin_amdgcn_mfma_f32_16x16x32_bf16(a, b1, acc[ft][1], 0, 0, 0);
            }
        }
        __builtin_amdgcn_s_setprio(0);
    };

    // ---- residual blocks (NO barriers: hnF wave-private, W from global)
    for (int blk = 0; blk < NBLK; ++blk) {
        // write h as packed bf16 into B-frag-order LDS (16 x ds_write_b64)
        #pragma unroll
        for (int ft = 0; ft < 8; ++ft) {
            const int foff = (ft >> 1) * 1024 + (ft & 1) * 256;
            #pragma unroll
            for (int rt = 0; rt < 2; ++rt) {
                uint2v v;
                v.x = pack_bf16(h[ft][rt][0], h[ft][rt][1]);
                v.y = pack_bf16(h[ft][rt][2], h[ft][rt][3]);
                *(uint2v*)&hnF[wbase + foff + rt * 512] = v;
            }
        }

        // hoist ALL 8 B-fragment reads (in-order DS pipe: reads issued after the
        // aliasing writes return new data; results land under the rmsnorm VALU)
        bf16x8 bfr[8];
        #pragma unroll
        for (int i = 0; i < 8; ++i)
            bfr[i] = __builtin_bit_cast(bf16x8, *(const ushort8*)&hnF[rbase + i * 512]);

        // rmsnorm scale per row: 4 partial sums (dep chain 8 FMA), then xor over q
        float rs[2];
        #pragma unroll
        for (int rt = 0; rt < 2; ++rt) {
            float p0 = 0.0f, p1 = 0.0f, p2 = 0.0f, p3 = 0.0f;
            #pragma unroll
            for (int ft = 0; ft < 8; ++ft) {
                p0 += h[ft][rt][0] * h[ft][rt][0];
                p1 += h[ft][rt][1] * h[ft][rt][1];
                p2 += h[ft][rt][2] * h[ft][rt][2];
                p3 += h[ft][rt][3] * h[ft][rt][3];
            }
            float ss = (p0 + p1) + (p2 + p3);
            ss += __shfl_xor(ss, 16, 64);
            ss += __shfl_xor(ss, 32, 64);
            rs[rt] = rsqrtf(ss * (1.0f / 128.0f) + 1.1920929e-7f);
        }

        // kt loop, static ping-pong: kt0 uses a0 (preloaded), kt3 prefetches
        // next blk's kt0 back into a0. B-frags come from the hoisted bfr[].
        const unsigned short* Wb = WbF + blk * 16384;
        ktstep(a0, a1, bfr[0], bfr[1], Wb + 1 * 4096, true);
        ktstep(a1, a0, bfr[2], bfr[3], Wb + 2 * 4096, false);
        ktstep(a0, a1, bfr[4], bfr[5], Wb + 3 * 4096, false);
        ktstep(a1, a0, bfr[6], bfr[7], blk < NBLK - 1 ? WbF + (blk + 1) * 16384 : nullptr, false);

        // epilogue: h += relu(rs[rt]*acc + b_res[f])
        const float4v* br4 = (const float4v*)(b_res + blk * HID);
        #pragma unroll
        for (int ft = 0; ft < 8; ++ft) {
            float4v bb = br4[ft * 4 + q];
            #pragma unroll
            for (int rt = 0; rt < 2; ++rt) {
                #pragma unroll
                for (int reg = 0; reg < 4; ++reg)
                    h[ft][rt][reg] += fmaxf(fmaf(rs[rt], acc[ft][rt][reg], bb[reg]), 0.0f);
            }
        }
    }

    // ---- output head: e[r] = exp(h[.][r] . W_out + b_out)
    const float bo = b_out[0];
    const float4v* wo4 = (const float4v*)W_out;
    float s[2] = {0.0f, 0.0f};
    #pragma unroll
    for (int ft = 0; ft < 8; ++ft) {
        float4v w = wo4[ft * 4 + q];
        #pragma unroll
        for (int rt = 0; rt < 2; ++rt) {
            #pragma unroll
            for (int reg = 0; reg < 4; ++reg)
                s[rt] += h[ft][rt][reg] * w[reg];
        }
    }
    #pragma unroll
    for (int rt = 0; rt < 2; ++rt) {
        s[rt] += __shfl_xor(s[rt], 16, 64);
        s[rt] += __shfl_xor(s[rt], 32, 64);
    }
    if (q == 0) {
        #pragma unroll
        for (int rt = 0; rt < 2; ++rt)
            e[rowbase + wave * 32 + rt * 16 + c] = __expf(s[rt] + bo);
    }
}

// ---- segment sum of e (sorted ids): wave-level segmented scan, tail lanes atomicAdd
__global__ void segsum_kernel(const float* __restrict__ e, const int* __restrict__ ids,
                              float* __restrict__ segsum) {
    int i = blockIdx.x * 256 + threadIdx.x;
    int lane = threadIdx.x & 63;
    float v = 0.0f; int id = -1;
    if (i < N_EDGES) { v = e[i]; id = ids[i]; }
    #pragma unroll
    for (int d = 1; d < 64; d <<= 1) {
        float ov = __shfl_up(v, d, 64);
        int oid = __shfl_up(id, d, 64);
        if (lane >= d && oid == id) v += ov;
    }
    int nid = __shfl_down(id, 1, 64);
    bool tail = (lane == 63) || (nid != id);
    if (id >= 0 && tail) atomicAdd(&segsum[id], v);
}

__global__ void norm_kernel(const float* __restrict__ e, const int* __restrict__ ids,
                            const float* __restrict__ segsum, float* __restrict__ out) {
    int i = blockIdx.x * 256 + threadIdx.x;
    if (i < N_EDGES) out[i] = e[i] / segsum[ids[i]];
}

extern "C" void kernel_launch(void* const* d_in, const int* in_sizes, int n_in,
                              void* d_out, int out_size, void* d_ws, size_t ws_size,
                              hipStream_t stream) {
    const float* x      = (const float*)d_in[0];
    const int*   ids    = (const int*)d_in[1];
    const float* W_in   = (const float*)d_in[2];
    const float* b_in   = (const float*)d_in[3];
    const float* rms_w  = (const float*)d_in[4];
    const float* W_res  = (const float*)d_in[5];
    const float* b_res  = (const float*)d_in[6];
    const float* W_out  = (const float*)d_in[7];
    const float* b_out  = (const float*)d_in[8];
    float* out = (float*)d_out;

    char* ws = (char*)d_ws;
    unsigned short* WbF = (unsigned short*)ws;                 // 131072 B
    float* Win4   = (float*)(ws + 131072);                     // 2048 B
    float* e      = (float*)(ws + 131072 + 2048);              // 8,000,000 B
    float* segsum = (float*)(ws + 131072 + 2048 + 8000000);    // 2,000,000 B

    int prep_items = 65536 + 128 + NUM_SEG;
    prep_kernel<<<(prep_items + 255) / 256, 256, 0, stream>>>(W_res, rms_w, W_in, b_in,
                                                              WbF, Win4, segsum);
    mlp_kernel<<<N_EDGES / 128, 256, 0, stream>>>(x, WbF, b_res, W_out, b_out, Win4, e);
    segsum_kernel<<<(N_EDGES + 255) / 256, 256, 0, stream>>>(e, ids, segsum);
    norm_kernel<<<(N_EDGES + 255) / 256, 256, 0, stream>>>(e, ids, segsum, out);
}